// Round 8
// baseline (452.018 us; speedup 1.0000x reference)
//
#include <hip/hip_runtime.h>

#define HDIM 128

typedef unsigned int uint;
typedef unsigned short ushort;
typedef __attribute__((ext_vector_type(8))) short short8;
typedef __attribute__((ext_vector_type(4))) float f32x4;

typedef __attribute__((address_space(3))) uint  lds_u32_t;
typedef const __attribute__((address_space(1))) uint g_u32_t;
#define GLDS16(gp, lp) __builtin_amdgcn_global_load_lds((g_u32_t*)(gp), (lds_u32_t*)(lp), 16, 0, 0)

// round-to-nearest-even float -> bf16 bits
__device__ inline ushort f2bf(float f) {
    uint u = __float_as_uint(f);
    uint rounding = 0x7fffu + ((u >> 16) & 1u);
    return (ushort)((u + rounding) >> 16);
}
__device__ inline float bf2f(ushort h) { return __uint_as_float(((uint)h) << 16); }

__device__ inline float4 bf4_to_f4(uint2 u) {
    float4 r;
    r.x = __uint_as_float(u.x << 16);
    r.y = __uint_as_float(u.x & 0xffff0000u);
    r.z = __uint_as_float(u.y << 16);
    r.w = __uint_as_float(u.y & 0xffff0000u);
    return r;
}

// ======================= CSR build =======================

__global__ __launch_bounds__(256) void k_count(const int* __restrict__ dst,
                                               int* __restrict__ cnt,
                                               int* __restrict__ rank, int e) {
    int i = blockIdx.x * 256 + threadIdx.x;
    if (i < e) rank[i] = atomicAdd(&cnt[dst[i]], 1);
}

__global__ __launch_bounds__(256) void k_dinv(const int* __restrict__ cnt,
                                              float* __restrict__ dinv, int n) {
    int i = blockIdx.x * 256 + threadIdx.x;
    if (i < n) dinv[i] = rsqrtf((float)(cnt[i] + 1));   // +1 self-loop
}

__global__ __launch_bounds__(256) void k_scan1(const int* __restrict__ cnt,
                                               int* __restrict__ offs,
                                               int* __restrict__ bsum, int n) {
    __shared__ int sm[256];
    int tid = threadIdx.x;
    int i = blockIdx.x * 256 + tid;
    int v = (i < n) ? cnt[i] : 0;
    sm[tid] = v;
    __syncthreads();
    for (int off = 1; off < 256; off <<= 1) {
        int t = (tid >= off) ? sm[tid - off] : 0;
        __syncthreads();
        sm[tid] += t;
        __syncthreads();
    }
    if (i < n) offs[i] = sm[tid] - v;
    if (tid == 255) bsum[blockIdx.x] = sm[255];
}

__global__ __launch_bounds__(512) void k_scan2(int* __restrict__ bsum, int nb) {
    __shared__ int sm[512];
    int tid = threadIdx.x;
    int v = (tid < nb) ? bsum[tid] : 0;
    sm[tid] = v;
    __syncthreads();
    for (int off = 1; off < 512; off <<= 1) {
        int t = (tid >= off) ? sm[tid - off] : 0;
        __syncthreads();
        sm[tid] += t;
        __syncthreads();
    }
    if (tid < nb) bsum[tid] = sm[tid] - v;
}

__global__ __launch_bounds__(256) void k_scan3(int* __restrict__ offs,
                                               const int* __restrict__ bsum,
                                               int n, int e) {
    int i = blockIdx.x * 256 + threadIdx.x;
    if (i < n) offs[i] += bsum[blockIdx.x];
    if (i == 0) offs[n] = e;
}

__global__ __launch_bounds__(256) void k_fill(const int* __restrict__ src,
                                              const int* __restrict__ dst,
                                              const int* __restrict__ offs,
                                              const int* __restrict__ rank,
                                              int* __restrict__ csr, int e) {
    int i = blockIdx.x * 256 + threadIdx.x;
    if (i < e) {
        csr[offs[dst[i]] + rank[i]] = src[i];
    }
}

// ===== W prep: split-transpose W[K][128] -> tile-major swizzled planes [K/32][128][32] =====
// 8-ushort unit u of row c stored at physical unit u ^ ((c>>1)&3).

__global__ __launch_bounds__(256) void k_prep_w(const float* __restrict__ W,
                                                ushort* __restrict__ wt_hi,
                                                ushort* __restrict__ wt_lo, int K) {
    int idx = blockIdx.x * 256 + threadIdx.x;
    if (idx < K * HDIM) {
        int k = idx >> 7;       // row in W (k index)
        int c = idx & 127;      // col in W
        float v = W[idx];
        ushort h = f2bf(v);
        ushort l = f2bf(v - bf2f(h));
        int kt = k >> 5, kk = k & 31;
        int pos = kt * 4096 + c * 32 + (kk ^ (((c >> 1) & 3) << 3));
        wt_hi[pos] = h;
        wt_lo[pos] = l;
    }
}

// =============== MFMA GEMM: g = bf16( dinv .* (X @ W) ), split-bf16 ===============
// Whole-K-resident LDS (128KB, 1 block/CU): stage ALL tiles with back-to-back
// glds (32 outstanding/wave), ONE barrier, then all K-subtile MFMA passes.
// K=256 (XF32): two 128-wide passes; X fp32 loaded/split in-kernel.
// 4 waves, 2x2 grid of 64x64; 16x16x32 MFMA, 3 terms (hh, hl, lh).

template<int K, bool XF32>
__global__ __launch_bounds__(256, 1) void k_mm(const float* __restrict__ Xf,
                                               const ushort* __restrict__ XH,
                                               const ushort* __restrict__ XL,
                                               const ushort* __restrict__ WH,
                                               const ushort* __restrict__ WL,
                                               const float* __restrict__ dinv,
                                               ushort* __restrict__ g, int n)
{
    __shared__ ushort lds[4][4][4096];   // [plane xh,xl,wh,wl][kt][128 rows * 32]

    const int tid  = threadIdx.x;
    const int wv   = tid >> 6;
    const int lane = tid & 63;
    const int r    = lane & 15;
    const int gq8  = (lane >> 4) * 8;
    const int row0 = blockIdx.x * 128;

    f32x4 acc[4][4];
    #pragma unroll
    for (int m = 0; m < 4; m++)
        #pragma unroll
        for (int nf = 0; nf < 4; nf++)
            acc[m][nf] = (f32x4){0.f, 0.f, 0.f, 0.f};

    const int xbase = (wv >> 1) * 64;
    const int wbase = (wv & 1) * 64;

    auto COMPUTE = [&](int kt) {
        const int sx = ((r >> 1) & 3) << 3;
        short8 bh[4], bl[4];
        #pragma unroll
        for (int nf = 0; nf < 4; nf++) {
            int off = (xbase + nf * 16 + r) * 32 + (gq8 ^ sx);
            bh[nf] = *(const short8*)&lds[0][kt][off];
            bl[nf] = *(const short8*)&lds[1][kt][off];
        }
        #pragma unroll
        for (int m = 0; m < 4; m++) {
            int off = (wbase + m * 16 + r) * 32 + (gq8 ^ sx);
            short8 ah = *(const short8*)&lds[2][kt][off];
            short8 al = *(const short8*)&lds[3][kt][off];
            #pragma unroll
            for (int nf = 0; nf < 4; nf++) {
                acc[m][nf] = __builtin_amdgcn_mfma_f32_16x16x32_bf16(ah, bh[nf], acc[m][nf], 0, 0, 0);
                acc[m][nf] = __builtin_amdgcn_mfma_f32_16x16x32_bf16(ah, bl[nf], acc[m][nf], 0, 0, 0);
                acc[m][nf] = __builtin_amdgcn_mfma_f32_16x16x32_bf16(al, bh[nf], acc[m][nf], 0, 0, 0);
            }
        }
    };

    if constexpr (!XF32) {
        // ---- single fill: each wave stages its 32KB plane, 32 glds back-to-back ----
        const ushort* plane = (wv == 0) ? XH : (wv == 1) ? XL : (wv == 2) ? WH : WL;
        const bool isX = (wv < 2);
        #pragma unroll
        for (int i = 0; i < 32; i++) {
            int kt = i >> 3, sub = i & 7;
            const ushort* src;
            if (isX) {
                int ro = row0 + sub * 16 + (lane >> 2);
                if (ro >= n) ro = 0;   // clamp; garbage rows discarded at epilogue
                src = plane + (size_t)kt * ((size_t)n * 32) + (size_t)ro * 32 + (lane & 3) * 8;
            } else {
                src = plane + kt * 4096 + sub * 512 + lane * 8;
            }
            GLDS16(src, &lds[wv][kt][sub * 512]);
        }
        __syncthreads();
        #pragma unroll
        for (int kt = 0; kt < 4; kt++) COMPUTE(kt);
    } else {
        // ---- K=256: two 128-wide passes; W via glds, X fp32 split in-kernel ----
        const int srow  = tid >> 1;
        const int shalf = tid & 1;
        const int grow  = row0 + srow;
        const bool ok   = grow < n;
        const int swz   = (srow >> 1) & 3;

        #pragma unroll
        for (int pass = 0; pass < K / 128; pass++) {
            if (pass) __syncthreads();     // previous compute done before overwrite
            // W glds (waves 2,3)
            if (wv >= 2) {
                const ushort* wp = (wv == 2) ? WH : WL;
                #pragma unroll
                for (int i = 0; i < 32; i++) {
                    int kt = i >> 3, sub = i & 7;
                    GLDS16(wp + (pass * 4 + kt) * 4096 + sub * 512 + lane * 8,
                           &lds[wv][kt][sub * 512]);
                }
            }
            // X: 16 float4 loads (all issued, pipelined)
            float4 xf[16];
            {
                const float4* xp = (const float4*)(Xf + (size_t)grow * K + pass * 128 + shalf * 16);
                #pragma unroll
                for (int j = 0; j < 4; j++)
                    #pragma unroll
                    for (int q = 0; q < 4; q++)
                        xf[j * 4 + q] = ok ? xp[j * 8 + q] : make_float4(0.f, 0.f, 0.f, 0.f);
            }
            // split + swizzled ds_write, per k-subtile
            #pragma unroll
            for (int j = 0; j < 4; j++) {
                float v[16];
                #pragma unroll
                for (int q = 0; q < 4; q++) {
                    v[q * 4 + 0] = xf[j * 4 + q].x; v[q * 4 + 1] = xf[j * 4 + q].y;
                    v[q * 4 + 2] = xf[j * 4 + q].z; v[q * 4 + 3] = xf[j * 4 + q].w;
                }
                uint h[8], l[8];
                #pragma unroll
                for (int q = 0; q < 8; q++) {
                    ushort h0 = f2bf(v[2 * q]), h1 = f2bf(v[2 * q + 1]);
                    h[q] = (uint)h0 | ((uint)h1 << 16);
                    ushort l0 = f2bf(v[2 * q] - bf2f(h0));
                    ushort l1 = f2bf(v[2 * q + 1] - bf2f(h1));
                    l[q] = (uint)l0 | ((uint)l1 << 16);
                }
                int uA = (2 * shalf) ^ swz;
                int uB = (2 * shalf + 1) ^ swz;
                *(uint4*)&lds[0][j][srow * 32 + uA * 8] = make_uint4(h[0], h[1], h[2], h[3]);
                *(uint4*)&lds[0][j][srow * 32 + uB * 8] = make_uint4(h[4], h[5], h[6], h[7]);
                *(uint4*)&lds[1][j][srow * 32 + uA * 8] = make_uint4(l[0], l[1], l[2], l[3]);
                *(uint4*)&lds[1][j][srow * 32 + uB * 8] = make_uint4(l[4], l[5], l[6], l[7]);
            }
            __syncthreads();               // drains W glds + X lds writes
            #pragma unroll
            for (int kt = 0; kt < 4; kt++) COMPUTE(kt);
        }
    }

    // ---- epilogue: D[wcol][xrow]; scale by dinv[xrow], store bf16 g[n][128] ----
    #pragma unroll
    for (int nf = 0; nf < 4; nf++) {
        int xrow = row0 + xbase + nf * 16 + r;
        if (xrow < n) {
            float di = dinv[xrow];
            #pragma unroll
            for (int m = 0; m < 4; m++) {
                int wcol = wbase + m * 16 + gq8 / 2;   // gq*4
                f32x4 a = acc[m][nf];
                uint2 pk;
                pk.x = (uint)f2bf(a[0] * di) | ((uint)f2bf(a[1] * di) << 16);
                pk.y = (uint)f2bf(a[2] * di) | ((uint)f2bf(a[3] * di) << 16);
                *(uint2*)(g + (size_t)xrow * HDIM + wcol) = pk;
            }
        }
    }
}

// ===== gather + finish: o = [relu](dinv*(g[d] + sum g[src]) + b) =====
// EMIT_SPLIT: write bf16 hi/lo activation planes, tile-major [4][n][32], swizzled.

template<bool RELU, bool EMIT_SPLIT>
__global__ __launch_bounds__(256) void k_gather(const ushort* __restrict__ g,
                                                const int* __restrict__ csr,
                                                const int* __restrict__ offs,
                                                const float* __restrict__ dinv,
                                                const float* __restrict__ bias,
                                                float* __restrict__ out,
                                                ushort* __restrict__ ah,
                                                ushort* __restrict__ al, int n)
{
    int t    = blockIdx.x * 256 + threadIdx.x;
    int node = t >> 5;
    int l    = t & 31;
    if (node >= n) return;

    int e0 = offs[node];
    int e1 = offs[node + 1];

    float4 acc = bf4_to_f4(*(const uint2*)(g + (size_t)node * HDIM + l * 4));

    int e = e0;
    for (; e + 4 <= e1; e += 4) {
        int s0 = csr[e], s1 = csr[e + 1], s2 = csr[e + 2], s3 = csr[e + 3];
        float4 v0 = bf4_to_f4(*(const uint2*)(g + (size_t)s0 * HDIM + l * 4));
        float4 v1 = bf4_to_f4(*(const uint2*)(g + (size_t)s1 * HDIM + l * 4));
        float4 v2 = bf4_to_f4(*(const uint2*)(g + (size_t)s2 * HDIM + l * 4));
        float4 v3 = bf4_to_f4(*(const uint2*)(g + (size_t)s3 * HDIM + l * 4));
        acc.x += v0.x + v1.x + v2.x + v3.x;
        acc.y += v0.y + v1.y + v2.y + v3.y;
        acc.z += v0.z + v1.z + v2.z + v3.z;
        acc.w += v0.w + v1.w + v2.w + v3.w;
    }
    for (; e < e1; e++) {
        int s = csr[e];
        float4 v = bf4_to_f4(*(const uint2*)(g + (size_t)s * HDIM + l * 4));
        acc.x += v.x; acc.y += v.y; acc.z += v.z; acc.w += v.w;
    }

    float di  = dinv[node];
    float4 bb = *(const float4*)(bias + l * 4);
    float4 o;
    o.x = fmaf(di, acc.x, bb.x);
    o.y = fmaf(di, acc.y, bb.y);
    o.z = fmaf(di, acc.z, bb.z);
    o.w = fmaf(di, acc.w, bb.w);
    if (RELU) {
        o.x = fmaxf(o.x, 0.f); o.y = fmaxf(o.y, 0.f);
        o.z = fmaxf(o.z, 0.f); o.w = fmaxf(o.w, 0.f);
    }
    if (EMIT_SPLIT) {
        ushort h0 = f2bf(o.x), h1 = f2bf(o.y), h2 = f2bf(o.z), h3 = f2bf(o.w);
        uint2 ph, pl;
        ph.x = (uint)h0 | ((uint)h1 << 16);
        ph.y = (uint)h2 | ((uint)h3 << 16);
        pl.x = (uint)f2bf(o.x - bf2f(h0)) | ((uint)f2bf(o.y - bf2f(h1)) << 16);
        pl.y = (uint)f2bf(o.z - bf2f(h2)) | ((uint)f2bf(o.w - bf2f(h3)) << 16);
        // tile-major [kt][n][32], swizzle: 4-ushort slot (l&7)*4 XOR'd on bits 3-4
        int kt = l >> 3;
        size_t base = (size_t)kt * n * 32 + (size_t)node * 32
                    + (((l & 7) * 4) ^ (((node >> 1) & 3) << 3));
        *(uint2*)(ah + base) = ph;
        *(uint2*)(al + base) = pl;
    } else {
        *(float4*)(out + (size_t)node * HDIM + l * 4) = o;
    }
}

// ======================= launch =======================

extern "C" void kernel_launch(void* const* d_in, const int* in_sizes, int n_in,
                              void* d_out, int out_size, void* d_ws, size_t ws_size,
                              hipStream_t stream)
{
    const float* x  = (const float*)d_in[0];
    const int*   ei = (const int*)d_in[1];
    const float* W1 = (const float*)d_in[2];
    const float* b1 = (const float*)d_in[3];
    const float* W2 = (const float*)d_in[4];
    const float* b2 = (const float*)d_in[5];
    const float* W3 = (const float*)d_in[6];
    const float* b3 = (const float*)d_in[7];
    float* out = (float*)d_out;

    const int n = in_sizes[0] / 256;   // IN = 256
    const int E = in_sizes[1] / 2;
    const int* src = ei;
    const int* dst = ei + E;

    // workspace layout (bytes):
    //   dinv @0, cnt @512K, offs @1M, bsum @1.5M, csr @1600K (6.4MB),
    //   rank @8M (6.4MB), wh @14.5M (128K slot), wl @14.75M,
    //   g @16M (25.7MB), xh2 @42M (25.7MB), xl2 @68M (25.7MB)
    char*   ws   = (char*)d_ws;
    float*  dinv = (float*)(ws);
    int*    cnt  = (int*)(ws + (512 << 10));
    int*    offs = (int*)(ws + (1 << 20));
    int*    bsum = (int*)(ws + 1536 * 1024);
    int*    csr  = (int*)(ws + 1600 * 1024);
    int*    rank = (int*)(ws + (size_t)(8 << 20));
    ushort* wh   = (ushort*)(ws + 14848 * 1024);
    ushort* wl   = (ushort*)(ws + 15104 * 1024);
    ushort* g    = (ushort*)(ws + (size_t)(16 << 20));
    ushort* xh2  = (ushort*)(ws + (size_t)(42 << 20));
    ushort* xl2  = (ushort*)(ws + (size_t)(68 << 20));

    dim3 blk(256);
    int ngrid = (n + 255) / 256;
    int egrid = (E + 255) / 256;

    // ---- CSR build + norms ----
    hipMemsetAsync(cnt, 0, (size_t)n * 4, stream);
    k_count<<<egrid, blk, 0, stream>>>(dst, cnt, rank, E);
    k_dinv<<<ngrid, blk, 0, stream>>>(cnt, dinv, n);
    k_scan1<<<ngrid, blk, 0, stream>>>(cnt, offs, bsum, n);
    k_scan2<<<1, 512, 0, stream>>>(bsum, ngrid);
    k_scan3<<<ngrid, blk, 0, stream>>>(offs, bsum, n, E);
    k_fill<<<egrid, blk, 0, stream>>>(src, dst, offs, rank, csr, E);

    int mm_grid  = (n + 127) / 128;
    int gat_grid = (int)(((size_t)n * 32 + 255) / 256);

    // layer 1 (K=256, fp32 X split in-kernel, 2 passes)
    k_prep_w<<<(256 * HDIM + 255) / 256, blk, 0, stream>>>(W1, wh, wl, 256);
    k_mm<256, true><<<mm_grid, blk, 0, stream>>>(x, nullptr, nullptr, wh, wl, dinv, g, n);
    k_gather<true, true><<<gat_grid, blk, 0, stream>>>(g, csr, offs, dinv, b1, nullptr, xh2, xl2, n);
    // layer 2 (K=128, whole-K resident)
    k_prep_w<<<(128 * HDIM + 255) / 256, blk, 0, stream>>>(W2, wh, wl, 128);
    k_mm<128, false><<<mm_grid, blk, 0, stream>>>(nullptr, xh2, xl2, wh, wl, dinv, g, n);
    k_gather<true, true><<<gat_grid, blk, 0, stream>>>(g, csr, offs, dinv, b2, nullptr, xh2, xl2, n);
    // layer 3 (K=128)
    k_prep_w<<<(128 * HDIM + 255) / 256, blk, 0, stream>>>(W3, wh, wl, 128);
    k_mm<128, false><<<mm_grid, blk, 0, stream>>>(nullptr, xh2, xl2, wh, wl, dinv, g, n);
    k_gather<false, false><<<gat_grid, blk, 0, stream>>>(g, csr, offs, dinv, b3, out, nullptr, nullptr, n);
}

// Round 9
// 402.812 us; speedup vs baseline: 1.1222x; 1.1222x over previous
//
#include <hip/hip_runtime.h>

#define HDIM 128

typedef unsigned int uint;
typedef unsigned short ushort;
typedef __attribute__((ext_vector_type(8))) short short8;
typedef __attribute__((ext_vector_type(4))) float f32x4;

typedef __attribute__((address_space(3))) uint  lds_u32_t;
typedef const __attribute__((address_space(1))) uint g_u32_t;
#define GLDS16(gp, lp) __builtin_amdgcn_global_load_lds((g_u32_t*)(gp), (lds_u32_t*)(lp), 16, 0, 0)

// round-to-nearest-even float -> bf16 bits
__device__ inline ushort f2bf(float f) {
    uint u = __float_as_uint(f);
    uint rounding = 0x7fffu + ((u >> 16) & 1u);
    return (ushort)((u + rounding) >> 16);
}
__device__ inline float bf2f(ushort h) { return __uint_as_float(((uint)h) << 16); }

__device__ inline float4 bf4_to_f4(uint2 u) {
    float4 r;
    r.x = __uint_as_float(u.x << 16);
    r.y = __uint_as_float(u.x & 0xffff0000u);
    r.z = __uint_as_float(u.y << 16);
    r.w = __uint_as_float(u.y & 0xffff0000u);
    return r;
}

// ======================= CSR build =======================

__global__ __launch_bounds__(256) void k_count(const int* __restrict__ dst,
                                               int* __restrict__ cnt,
                                               int* __restrict__ rank, int e) {
    int i = blockIdx.x * 256 + threadIdx.x;
    if (i < e) rank[i] = atomicAdd(&cnt[dst[i]], 1);
}

__global__ __launch_bounds__(256) void k_dinv(const int* __restrict__ cnt,
                                              float* __restrict__ dinv, int n) {
    int i = blockIdx.x * 256 + threadIdx.x;
    if (i < n) dinv[i] = rsqrtf((float)(cnt[i] + 1));   // +1 self-loop
}

__global__ __launch_bounds__(256) void k_scan1(const int* __restrict__ cnt,
                                               int* __restrict__ offs,
                                               int* __restrict__ bsum, int n) {
    __shared__ int sm[256];
    int tid = threadIdx.x;
    int i = blockIdx.x * 256 + tid;
    int v = (i < n) ? cnt[i] : 0;
    sm[tid] = v;
    __syncthreads();
    for (int off = 1; off < 256; off <<= 1) {
        int t = (tid >= off) ? sm[tid - off] : 0;
        __syncthreads();
        sm[tid] += t;
        __syncthreads();
    }
    if (i < n) offs[i] = sm[tid] - v;
    if (tid == 255) bsum[blockIdx.x] = sm[255];
}

__global__ __launch_bounds__(512) void k_scan2(int* __restrict__ bsum, int nb) {
    __shared__ int sm[512];
    int tid = threadIdx.x;
    int v = (tid < nb) ? bsum[tid] : 0;
    sm[tid] = v;
    __syncthreads();
    for (int off = 1; off < 512; off <<= 1) {
        int t = (tid >= off) ? sm[tid - off] : 0;
        __syncthreads();
        sm[tid] += t;
        __syncthreads();
    }
    if (tid < nb) bsum[tid] = sm[tid] - v;
}

__global__ __launch_bounds__(256) void k_scan3(int* __restrict__ offs,
                                               const int* __restrict__ bsum,
                                               int n, int e) {
    int i = blockIdx.x * 256 + threadIdx.x;
    if (i < n) offs[i] += bsum[blockIdx.x];
    if (i == 0) offs[n] = e;
}

__global__ __launch_bounds__(256) void k_fill(const int* __restrict__ src,
                                              const int* __restrict__ dst,
                                              const int* __restrict__ offs,
                                              const int* __restrict__ rank,
                                              int* __restrict__ csr, int e) {
    int i = blockIdx.x * 256 + threadIdx.x;
    if (i < e) {
        csr[offs[dst[i]] + rank[i]] = src[i];
    }
}

// ===== W prep: split-transpose W[K][128] -> tile-major swizzled planes [K/32][128][32] =====
// 8-ushort unit u of row c stored at physical unit u ^ ((c>>1)&3).

__global__ __launch_bounds__(256) void k_prep_w(const float* __restrict__ W,
                                                ushort* __restrict__ wt_hi,
                                                ushort* __restrict__ wt_lo, int K) {
    int idx = blockIdx.x * 256 + threadIdx.x;
    if (idx < K * HDIM) {
        int k = idx >> 7;       // row in W (k index)
        int c = idx & 127;      // col in W
        float v = W[idx];
        ushort h = f2bf(v);
        ushort l = f2bf(v - bf2f(h));
        int kt = k >> 5, kk = k & 31;
        int pos = kt * 4096 + c * 32 + (kk ^ (((c >> 1) & 3) << 3));
        wt_hi[pos] = h;
        wt_lo[pos] = l;
    }
}

// =============== MFMA GEMM: g = bf16( dinv .* (X @ W) ), split-bf16 ===============
// Latency-tolerant structure: X NEVER staged in LDS — each wave owns one 16-row
// tile and loads its MFMA B-fragments directly from global (tile-major planes
// make each load a coalesced 1KB wave read). Only W lives in LDS (staged once
// per block via glds, ONE barrier, swizzled reads = conflict-free).
// 512 threads = 8 waves; wave computes 16 rows x 128 cols (8 col-frags);
// 16x16x32 MFMA, 3 terms (Wh*Xh + Wh*Xl + Wl*Xh).

template<int K, bool XF32>
__global__ __launch_bounds__(512, XF32 ? 2 : 4)
void k_mm(const float* __restrict__ Xf,
          const ushort* __restrict__ XH,
          const ushort* __restrict__ XL,
          const ushort* __restrict__ WH,
          const ushort* __restrict__ WL,
          const float* __restrict__ dinv,
          ushort* __restrict__ g, int n)
{
    constexpr int NKT = K / 32;
    __shared__ ushort lds[2][NKT][128][32];   // W^T hi/lo, tile-major, pre-swizzled

    const int tid  = threadIdx.x;
    const int wv   = tid >> 6;
    const int lane = tid & 63;
    const int r    = lane & 15;
    const int gq   = lane >> 4;
    const int sw   = (r >> 1) & 3;            // swizzle class (matches prep/emit)

    // ---- stage W planes: linear glds memcpy (planes are pre-swizzled) ----
    {
        const ushort* plane = (tid < 256) ? WH : WL;
        ushort* dstp = (tid < 256) ? &lds[0][0][0][0] : &lds[1][0][0][0];
        int t = tid & 255;
        constexpr int CH = (NKT * 4096) / (256 * 8);   // 16B chunks per thread
        #pragma unroll
        for (int i = 0; i < CH; i++) {
            int off = (i * 256 + t) * 8;
            GLDS16(plane + off, dstp + off);
        }
    }

    const int tile = blockIdx.x * 8 + wv;
    const int ntiles = (n + 15) / 16;
    const bool active = tile < ntiles;
    const int row0 = active ? tile * 16 : 0;
    int rowr = row0 + r; if (rowr >= n) rowr = n - 1;   // clamped load row

    f32x4 acc[8];
    #pragma unroll
    for (int m = 0; m < 8; m++) acc[m] = (f32x4){0.f, 0.f, 0.f, 0.f};

    if constexpr (!XF32) {
        // ---- issue all X fragment loads (coalesced 16B/lane) before barrier ----
        short8 xh8[NKT], xl8[NKT];
        const size_t n32 = (size_t)n * 32;
        const size_t rowoff = (size_t)rowr * 32 + (size_t)(gq ^ sw) * 8;
        #pragma unroll
        for (int kt = 0; kt < NKT; kt++) {
            xh8[kt] = *(const short8*)(XH + (size_t)kt * n32 + rowoff);
            xl8[kt] = *(const short8*)(XL + (size_t)kt * n32 + rowoff);
        }
        __syncthreads();   // W resident (also drains X loads; they're needed now anyway)

        #pragma unroll
        for (int kt = 0; kt < NKT; kt++) {
            #pragma unroll
            for (int m = 0; m < 8; m++) {
                short8 ah = *(const short8*)&lds[0][kt][m * 16 + r][(gq ^ sw) * 8];
                short8 al = *(const short8*)&lds[1][kt][m * 16 + r][(gq ^ sw) * 8];
                acc[m] = __builtin_amdgcn_mfma_f32_16x16x32_bf16(ah, xh8[kt], acc[m], 0, 0, 0);
                acc[m] = __builtin_amdgcn_mfma_f32_16x16x32_bf16(ah, xl8[kt], acc[m], 0, 0, 0);
                acc[m] = __builtin_amdgcn_mfma_f32_16x16x32_bf16(al, xh8[kt], acc[m], 0, 0, 0);
            }
        }
    } else {
        // ---- layer 1: X fp32 direct loads, split in-register ----
        float4 xf[2 * NKT];
        const float4* xp = (const float4*)(Xf + (size_t)rowr * K);
        #pragma unroll
        for (int kt = 0; kt < NKT; kt++) {
            xf[kt * 2]     = xp[kt * 8 + gq * 2];
            xf[kt * 2 + 1] = xp[kt * 8 + gq * 2 + 1];
        }
        __syncthreads();   // W resident

        #pragma unroll
        for (int kt = 0; kt < NKT; kt++) {
            float v[8] = {xf[kt*2].x, xf[kt*2].y, xf[kt*2].z, xf[kt*2].w,
                          xf[kt*2+1].x, xf[kt*2+1].y, xf[kt*2+1].z, xf[kt*2+1].w};
            short8 bh, bl;
            #pragma unroll
            for (int q = 0; q < 8; q++) {
                ushort h = f2bf(v[q]);
                bh[q] = (short)h;
                bl[q] = (short)f2bf(v[q] - bf2f(h));
            }
            #pragma unroll
            for (int m = 0; m < 8; m++) {
                short8 ah = *(const short8*)&lds[0][kt][m * 16 + r][(gq ^ sw) * 8];
                short8 al = *(const short8*)&lds[1][kt][m * 16 + r][(gq ^ sw) * 8];
                acc[m] = __builtin_amdgcn_mfma_f32_16x16x32_bf16(ah, bh, acc[m], 0, 0, 0);
                acc[m] = __builtin_amdgcn_mfma_f32_16x16x32_bf16(ah, bl, acc[m], 0, 0, 0);
                acc[m] = __builtin_amdgcn_mfma_f32_16x16x32_bf16(al, bh, acc[m], 0, 0, 0);
            }
        }
    }

    // ---- epilogue: D[wcol][xrow]; col(lane&15)=xrow, row(gq*4+j)=wcol ----
    int row = row0 + r;
    if (active && row < n) {
        float di = dinv[row];
        #pragma unroll
        for (int m = 0; m < 8; m++) {
            int wcol = m * 16 + gq * 4;
            f32x4 a = acc[m];
            uint2 pk;
            pk.x = (uint)f2bf(a[0] * di) | ((uint)f2bf(a[1] * di) << 16);
            pk.y = (uint)f2bf(a[2] * di) | ((uint)f2bf(a[3] * di) << 16);
            *(uint2*)(g + (size_t)row * HDIM + wcol) = pk;
        }
    }
}

// ===== gather + finish: o = [relu](dinv*(g[d] + sum g[src]) + b) =====
// EMIT_SPLIT: write bf16 hi/lo activation planes, tile-major [4][n][32], swizzled.

template<bool RELU, bool EMIT_SPLIT>
__global__ __launch_bounds__(256) void k_gather(const ushort* __restrict__ g,
                                                const int* __restrict__ csr,
                                                const int* __restrict__ offs,
                                                const float* __restrict__ dinv,
                                                const float* __restrict__ bias,
                                                float* __restrict__ out,
                                                ushort* __restrict__ ah,
                                                ushort* __restrict__ al, int n)
{
    int t    = blockIdx.x * 256 + threadIdx.x;
    int node = t >> 5;
    int l    = t & 31;
    if (node >= n) return;

    int e0 = offs[node];
    int e1 = offs[node + 1];

    float4 acc = bf4_to_f4(*(const uint2*)(g + (size_t)node * HDIM + l * 4));

    int e = e0;
    for (; e + 4 <= e1; e += 4) {
        int s0 = csr[e], s1 = csr[e + 1], s2 = csr[e + 2], s3 = csr[e + 3];
        float4 v0 = bf4_to_f4(*(const uint2*)(g + (size_t)s0 * HDIM + l * 4));
        float4 v1 = bf4_to_f4(*(const uint2*)(g + (size_t)s1 * HDIM + l * 4));
        float4 v2 = bf4_to_f4(*(const uint2*)(g + (size_t)s2 * HDIM + l * 4));
        float4 v3 = bf4_to_f4(*(const uint2*)(g + (size_t)s3 * HDIM + l * 4));
        acc.x += v0.x + v1.x + v2.x + v3.x;
        acc.y += v0.y + v1.y + v2.y + v3.y;
        acc.z += v0.z + v1.z + v2.z + v3.z;
        acc.w += v0.w + v1.w + v2.w + v3.w;
    }
    for (; e < e1; e++) {
        int s = csr[e];
        float4 v = bf4_to_f4(*(const uint2*)(g + (size_t)s * HDIM + l * 4));
        acc.x += v.x; acc.y += v.y; acc.z += v.z; acc.w += v.w;
    }

    float di  = dinv[node];
    float4 bb = *(const float4*)(bias + l * 4);
    float4 o;
    o.x = fmaf(di, acc.x, bb.x);
    o.y = fmaf(di, acc.y, bb.y);
    o.z = fmaf(di, acc.z, bb.z);
    o.w = fmaf(di, acc.w, bb.w);
    if (RELU) {
        o.x = fmaxf(o.x, 0.f); o.y = fmaxf(o.y, 0.f);
        o.z = fmaxf(o.z, 0.f); o.w = fmaxf(o.w, 0.f);
    }
    if (EMIT_SPLIT) {
        ushort h0 = f2bf(o.x), h1 = f2bf(o.y), h2 = f2bf(o.z), h3 = f2bf(o.w);
        uint2 ph, pl;
        ph.x = (uint)h0 | ((uint)h1 << 16);
        ph.y = (uint)h2 | ((uint)h3 << 16);
        pl.x = (uint)f2bf(o.x - bf2f(h0)) | ((uint)f2bf(o.y - bf2f(h1)) << 16);
        pl.y = (uint)f2bf(o.z - bf2f(h2)) | ((uint)f2bf(o.w - bf2f(h3)) << 16);
        // tile-major [kt][n][32], swizzle on 8-ushort units via (node>>1)&3
        int kt = l >> 3;
        size_t base = (size_t)kt * n * 32 + (size_t)node * 32
                    + (((l & 7) * 4) ^ (((node >> 1) & 3) << 3));
        *(uint2*)(ah + base) = ph;
        *(uint2*)(al + base) = pl;
    } else {
        *(float4*)(out + (size_t)node * HDIM + l * 4) = o;
    }
}

// ======================= launch =======================

extern "C" void kernel_launch(void* const* d_in, const int* in_sizes, int n_in,
                              void* d_out, int out_size, void* d_ws, size_t ws_size,
                              hipStream_t stream)
{
    const float* x  = (const float*)d_in[0];
    const int*   ei = (const int*)d_in[1];
    const float* W1 = (const float*)d_in[2];
    const float* b1 = (const float*)d_in[3];
    const float* W2 = (const float*)d_in[4];
    const float* b2 = (const float*)d_in[5];
    const float* W3 = (const float*)d_in[6];
    const float* b3 = (const float*)d_in[7];
    float* out = (float*)d_out;

    const int n = in_sizes[0] / 256;   // IN = 256
    const int E = in_sizes[1] / 2;
    const int* src = ei;
    const int* dst = ei + E;

    // workspace layout (bytes):
    //   dinv @0, cnt @512K, offs @1M, bsum @1.5M, csr @1600K (6.4MB),
    //   rank @8M (6.4MB), wh @14.5M (256K slot), wl @14.75M,
    //   g @16M (25.7MB), xh2 @42M (25.7MB), xl2 @68M (25.7MB)
    char*   ws   = (char*)d_ws;
    float*  dinv = (float*)(ws);
    int*    cnt  = (int*)(ws + (512 << 10));
    int*    offs = (int*)(ws + (1 << 20));
    int*    bsum = (int*)(ws + 1536 * 1024);
    int*    csr  = (int*)(ws + 1600 * 1024);
    int*    rank = (int*)(ws + (size_t)(8 << 20));
    ushort* wh   = (ushort*)(ws + 14848 * 1024);
    ushort* wl   = (ushort*)(ws + 15104 * 1024);
    ushort* g    = (ushort*)(ws + (size_t)(16 << 20));
    ushort* xh2  = (ushort*)(ws + (size_t)(42 << 20));
    ushort* xl2  = (ushort*)(ws + (size_t)(68 << 20));

    dim3 blk(256);
    int ngrid = (n + 255) / 256;
    int egrid = (E + 255) / 256;

    // ---- CSR build + norms ----
    hipMemsetAsync(cnt, 0, (size_t)n * 4, stream);
    k_count<<<egrid, blk, 0, stream>>>(dst, cnt, rank, E);
    k_dinv<<<ngrid, blk, 0, stream>>>(cnt, dinv, n);
    k_scan1<<<ngrid, blk, 0, stream>>>(cnt, offs, bsum, n);
    k_scan2<<<1, 512, 0, stream>>>(bsum, ngrid);
    k_scan3<<<ngrid, blk, 0, stream>>>(offs, bsum, n, E);
    k_fill<<<egrid, blk, 0, stream>>>(src, dst, offs, rank, csr, E);

    int ntiles  = (n + 15) / 16;
    int mm_grid = (ntiles + 7) / 8;
    int gat_grid = (int)(((size_t)n * 32 + 255) / 256);

    // layer 1 (K=256, fp32 X direct + in-register split)
    k_prep_w<<<(256 * HDIM + 255) / 256, blk, 0, stream>>>(W1, wh, wl, 256);
    k_mm<256, true><<<mm_grid, 512, 0, stream>>>(x, nullptr, nullptr, wh, wl, dinv, g, n);
    k_gather<true, true><<<gat_grid, blk, 0, stream>>>(g, csr, offs, dinv, b1, nullptr, xh2, xl2, n);
    // layer 2 (K=128, bf16 planes, X direct-to-register)
    k_prep_w<<<(128 * HDIM + 255) / 256, blk, 0, stream>>>(W2, wh, wl, 128);
    k_mm<128, false><<<mm_grid, 512, 0, stream>>>(nullptr, xh2, xl2, wh, wl, dinv, g, n);
    k_gather<true, true><<<gat_grid, blk, 0, stream>>>(g, csr, offs, dinv, b2, nullptr, xh2, xl2, n);
    // layer 3 (K=128)
    k_prep_w<<<(128 * HDIM + 255) / 256, blk, 0, stream>>>(W3, wh, wl, 128);
    k_mm<128, false><<<mm_grid, 512, 0, stream>>>(nullptr, xh2, xl2, wh, wl, dinv, g, n);
    k_gather<false, false><<<gat_grid, blk, 0, stream>>>(g, csr, offs, dinv, b3, out, nullptr, nullptr, n);
}